// Round 1
// baseline (235.825 us; speedup 1.0000x reference)
//
#include <hip/hip_runtime.h>
#include <math.h>

#define BB 256      // batch of mentions
#define LL 8        // tokens per mention
#define DD 200      // embedding dim
#define NN 100000   // concepts
#define TILE_N 64
#define KC 8
#define NTILES ((NN + TILE_N - 1) / TILE_N)   // 1563
#define GRID_MAIN 782

// ---------------- Phase 1: mention_rep (transposed) + m_norm ----------------
__global__ __launch_bounds__(256) void mention_kernel(
    const int* __restrict__ ids, const float* __restrict__ we,
    float* __restrict__ repT, float* __restrict__ mnorm) {
  int m = blockIdx.x;
  int d = threadIdx.x;
  __shared__ float red[4];
  float r = 0.f;
  if (d < DD) {
    int base = m * LL;
#pragma unroll
    for (int l = 0; l < LL; ++l) {
      int id = ids[base + l];
      r += we[(size_t)id * DD + d];
    }
    r *= (1.0f / LL);
    repT[d * BB + m] = r;
  }
  float sq = (d < DD) ? r * r : 0.f;
#pragma unroll
  for (int off = 32; off; off >>= 1) sq += __shfl_down(sq, off);
  int lane = threadIdx.x & 63, wid = threadIdx.x >> 6;
  if (lane == 0) red[wid] = sq;
  __syncthreads();
  if (threadIdx.x == 0) {
    float s = red[0] + red[1] + red[2] + red[3];
    mnorm[m] = sqrtf(s);
  }
}

// ---------------- Phase 2: tiled sims + per-block argmax ----------------
__global__ __launch_bounds__(256) void sim_kernel(
    const float* __restrict__ dict, const float* __restrict__ repT,
    const float* __restrict__ mnorm, float* __restrict__ pvals,
    int* __restrict__ pidx) {
  __shared__ float Ms[KC][BB];          // 8 KB
  __shared__ float Ds[KC][TILE_N + 4];  // pad 4: bank-spread + 16B align
  __shared__ float cnorm_s[TILE_N];

  int tid = threadIdx.x;
  int ng = tid & 7;        // n-group (8 concepts each)
  int mg = tid >> 3;       // m-group (8 mentions each)
  int m_base = mg * 8;
  int n_loc = ng * 8;

  float mn[8];
#pragma unroll
  for (int i = 0; i < 8; ++i) mn[i] = mnorm[m_base + i];

  float bestv[8];
  int besti[8];
#pragma unroll
  for (int i = 0; i < 8; ++i) { bestv[i] = -INFINITY; besti[i] = 0x7fffffff; }

  for (int tile = blockIdx.x; tile < NTILES; tile += GRID_MAIN) {
    int n0 = tile * TILE_N;
    __syncthreads();  // protect cnorm_s/Ms/Ds from previous tile's readers

    // ---- c_norm pre-pass: 4 threads per concept, float4 loads ----
    {
      int nl = tid >> 2;
      int part = tid & 3;
      int n = n0 + nl;
      float s = 0.f;
      if (n < NN) {
        const float4* row = reinterpret_cast<const float4*>(dict + (size_t)n * DD);
#pragma unroll
        for (int e4 = part; e4 < DD / 4; e4 += 4) {
          float4 v = row[e4];
          s += v.x * v.x + v.y * v.y + v.z * v.z + v.w * v.w;
        }
      }
      s += __shfl_xor(s, 1);
      s += __shfl_xor(s, 2);
      if (part == 0) cnorm_s[nl] = sqrtf(s);
    }

    float acc[8][8];
#pragma unroll
    for (int i = 0; i < 8; ++i)
#pragma unroll
      for (int j = 0; j < 8; ++j) acc[i][j] = 0.f;

    for (int k0 = 0; k0 < DD; k0 += KC) {
      __syncthreads();
      // stage mention tile: coalesced 1KB per k
#pragma unroll
      for (int k = 0; k < KC; ++k) Ms[k][tid] = repT[(k0 + k) * BB + tid];
      // stage dict tile: 512 elems, 2 per thread
#pragma unroll
      for (int e = 0; e < 2; ++e) {
        int idx = tid + e * 256;
        int nl = idx >> 3;
        int kk = idx & 7;
        int n = n0 + nl;
        Ds[kk][nl] = (n < NN) ? dict[(size_t)n * DD + k0 + kk] : 0.f;
      }
      __syncthreads();
#pragma unroll
      for (int k = 0; k < KC; ++k) {
        float4 m0 = *reinterpret_cast<const float4*>(&Ms[k][m_base]);
        float4 m1 = *reinterpret_cast<const float4*>(&Ms[k][m_base + 4]);
        float4 n0v = *reinterpret_cast<const float4*>(&Ds[k][n_loc]);
        float4 n1v = *reinterpret_cast<const float4*>(&Ds[k][n_loc + 4]);
        float mv[8] = {m0.x, m0.y, m0.z, m0.w, m1.x, m1.y, m1.z, m1.w};
        float nv[8] = {n0v.x, n0v.y, n0v.z, n0v.w, n1v.x, n1v.y, n1v.z, n1v.w};
#pragma unroll
        for (int i = 0; i < 8; ++i)
#pragma unroll
          for (int j = 0; j < 8; ++j) acc[i][j] = fmaf(mv[i], nv[j], acc[i][j]);
      }
    }

    // ---- epilogue: cosine + running best ----
#pragma unroll
    for (int j = 0; j < 8; ++j) {
      int n = n0 + n_loc + j;
      float cn = cnorm_s[n_loc + j];
      bool valid = (n < NN);
#pragma unroll
      for (int i = 0; i < 8; ++i) {
        float denom = fmaxf(mn[i] * cn, 1e-8f);
        float sim = valid ? (acc[i][j] / denom) : -INFINITY;
        if (sim > bestv[i] || (sim == bestv[i] && n < besti[i])) {
          bestv[i] = sim;
          besti[i] = n;
        }
      }
    }
  }

  // reduce across the 8 n-groups (adjacent lanes in-wave)
#pragma unroll
  for (int i = 0; i < 8; ++i) {
    float v = bestv[i];
    int ix = besti[i];
#pragma unroll
    for (int off = 1; off < 8; off <<= 1) {
      float v2 = __shfl_xor(v, off);
      int ix2 = __shfl_xor(ix, off);
      if (v2 > v || (v2 == v && ix2 < ix)) { v = v2; ix = ix2; }
    }
    bestv[i] = v;
    besti[i] = ix;
  }
  if (ng == 0) {
#pragma unroll
    for (int i = 0; i < 8; ++i) {
      pvals[blockIdx.x * BB + m_base + i] = bestv[i];
      pidx[blockIdx.x * BB + m_base + i] = besti[i];
    }
  }
}

// ---------------- Phase 3: final reduce over blocks ----------------
__global__ __launch_bounds__(256) void reduce_kernel(
    const float* __restrict__ pvals, const int* __restrict__ pidx,
    float* __restrict__ out) {
  int m = blockIdx.x;
  int tid = threadIdx.x;
  float v = -INFINITY;
  int ix = 0x7fffffff;
  for (int b = tid; b < GRID_MAIN; b += 256) {
    float v2 = pvals[b * BB + m];
    int ix2 = pidx[b * BB + m];
    if (v2 > v || (v2 == v && ix2 < ix)) { v = v2; ix = ix2; }
  }
  __shared__ float sv[256];
  __shared__ int si[256];
  sv[tid] = v;
  si[tid] = ix;
  __syncthreads();
  for (int off = 128; off; off >>= 1) {
    if (tid < off) {
      float v2 = sv[tid + off];
      int ix2 = si[tid + off];
      if (v2 > sv[tid] || (v2 == sv[tid] && ix2 < si[tid])) {
        sv[tid] = v2;
        si[tid] = ix2;
      }
    }
    __syncthreads();
  }
  if (tid == 0) {
    out[m] = sv[0];
    out[BB + m] = (float)si[0];  // indices written as float32 (flat f32 readback)
  }
}

extern "C" void kernel_launch(void* const* d_in, const int* in_sizes, int n_in,
                              void* d_out, int out_size, void* d_ws, size_t ws_size,
                              hipStream_t stream) {
  const int* ids = (const int*)d_in[0];
  const float* we = (const float*)d_in[1];
  const float* dict = (const float*)d_in[2];
  float* out = (float*)d_out;

  char* ws = (char*)d_ws;
  float* repT = (float*)ws;                            // 200*256*4 = 204800
  float* mnorm = (float*)(ws + 204800);                // 1024
  float* pvals = (float*)(ws + 208896);                // 782*256*4 = 800768
  int* pidx = (int*)(ws + 208896 + GRID_MAIN * BB * 4);

  mention_kernel<<<BB, 256, 0, stream>>>(ids, we, repT, mnorm);
  sim_kernel<<<GRID_MAIN, 256, 0, stream>>>(dict, repT, mnorm, pvals, pidx);
  reduce_kernel<<<BB, 256, 0, stream>>>(pvals, pidx, out);
}

// Round 2
// 217.564 us; speedup vs baseline: 1.0839x; 1.0839x over previous
//
#include <hip/hip_runtime.h>
#include <math.h>

#define BB 256
#define LL 8
#define DD 200
#define NN 100000
#define KP 224                      // K padded to 7*32
#define KT 7                        // k-tiles of 32
#define BN 64                       // concepts per block tile
#define NT ((NN + BN - 1) / BN)     // 1563 tiles

typedef __attribute__((ext_vector_type(8))) __bf16 bf16x8;
typedef __attribute__((ext_vector_type(16))) float f32x16;

// Granule-level (16B) bank-conflict-free permutation for [rows][32 bf16] tiles.
// slot(row,g): line=row>>1 picks 128B pair-line, bit2=row&1, low2=g^(row>>1).
// For 32 consecutive rows at fixed g: all 8 granule positions hit exactly 4x
// -> ds_read_b128 at the structural 4-phase minimum, zero extra conflicts.
__device__ __forceinline__ int swz(int row, int g) {
  return ((row >> 1) << 3) | ((row & 1) << 2) | ((g ^ (row >> 1)) & 3);
}

// fp32 -> bf16 round-to-nearest-even (bit exact, no header dependence)
__device__ __forceinline__ unsigned short f2bf(float x) {
  unsigned u = __float_as_uint(x);
  u = (u + 0x7fffu + ((u >> 16) & 1u)) >> 16;
  return (unsigned short)u;
}

// numpy argmax semantics: larger value wins; exact tie -> smaller index
__device__ __forceinline__ bool better(float a, int ia, float b, int ib) {
  return (a > b) || (a == b && ia < ib);
}

// ---------------- Phase 1: mention rep (fp32 + swizzled bf16 plane) ----------
__global__ __launch_bounds__(256) void prep_kernel(
    const int* __restrict__ ids, const float* __restrict__ we,
    float* __restrict__ repf, unsigned short* __restrict__ abf,
    float* __restrict__ mnorm) {
  int m = blockIdx.x, d = threadIdx.x;
  __shared__ float red[4];
  float r = 0.f;
  if (d < DD) {
    int base = m * LL;
#pragma unroll
    for (int l2 = 0; l2 < LL; ++l2) r += we[(size_t)ids[base + l2] * DD + d];
    r *= 0.125f;
    repf[m * DD + d] = r;
  }
  if (d < KP) {  // zero-pad k in [200,224)
    int t = d >> 5, g = (d & 31) >> 3, wo = d & 7;
    abf[t * 8192 + swz(m, g) * 8 + wo] = f2bf(d < DD ? r : 0.f);
  }
  float sq = (d < DD) ? r * r : 0.f;
#pragma unroll
  for (int off = 32; off; off >>= 1) sq += __shfl_down(sq, off);
  if ((threadIdx.x & 63) == 0) red[threadIdx.x >> 6] = sq;
  __syncthreads();
  if (threadIdx.x == 0) mnorm[m] = sqrtf(red[0] + red[1] + red[2] + red[3]);
}

// ---------------- Phase 2: bf16 MFMA sims, top-2 per (m, tile) ---------------
__global__ __launch_bounds__(512) void sim_kernel(
    const float* __restrict__ dict, const uint4* __restrict__ abf4,
    const float* __restrict__ mnorm, float4* __restrict__ partial) {
  __shared__ uint4 A_s[2][1024];      // 2 x 16KB  (256 rows x 32 k bf16, swizzled)
  __shared__ uint4 B_s[2][256];       // 2 x 4KB   (64 rows x 32 k bf16, swizzled)
  __shared__ float cn_s[BN];
  __shared__ float mn_s[BB];
  __shared__ float4 red_s[BB][2];     // 8KB cross-wn merge

  int tile = blockIdx.x;
  int n0 = tile * BN;
  int tid = threadIdx.x;
  int w = tid >> 6, l = tid & 63;
  int wm = w >> 1, wn = w & 1;        // 4 m-waves x 2 n-waves; wave tile 64x32

  if (tid < BB) mn_s[tid] = mnorm[tid];

  // B stager role: thread -> (concept row, 4-float k-quad)
  int brow = tid >> 3, q = tid & 7;
  int bn_ = n0 + brow;
  const bool bok = (bn_ < NN);
  const float* bsrc = dict + (size_t)(bok ? bn_ : 0) * DD;
  int bslot = swz(brow, q >> 1) * 2 + (q & 1);   // uint2 slot in B tile

  float sq = 0.f;
  f32x16 acc0, acc1;
#pragma unroll
  for (int i = 0; i < 16; ++i) { acc0[i] = 0.f; acc1[i] = 0.f; }

  uint4 av0, av1; float4 bv;
  // ---- prologue: stage step 0 into buf 0 ----
  av0 = abf4[tid];
  av1 = abf4[tid + 512];
  { int k = q * 4;
    if (bok && k < DD) bv = *(const float4*)(bsrc + k); else bv = make_float4(0.f,0.f,0.f,0.f); }
  A_s[0][tid] = av0; A_s[0][tid + 512] = av1;
  { sq += bv.x*bv.x + bv.y*bv.y + bv.z*bv.z + bv.w*bv.w;
    uint2 p; p.x = (unsigned)f2bf(bv.x) | ((unsigned)f2bf(bv.y) << 16);
    p.y = (unsigned)f2bf(bv.z) | ((unsigned)f2bf(bv.w) << 16);
    ((uint2*)B_s[0])[bslot] = p; }
  __syncthreads();

  for (int s = 0; s < KT; ++s) {
    int cur = s & 1;
    if (s + 1 < KT) {   // issue next-step global loads early (hide under MFMA)
      av0 = abf4[(s + 1) * 1024 + tid];
      av1 = abf4[(s + 1) * 1024 + tid + 512];
      int k = (s + 1) * 32 + q * 4;
      if (bok && k < DD) bv = *(const float4*)(bsrc + k); else bv = make_float4(0.f,0.f,0.f,0.f);
    }
    // ---- compute current buffer: 6 ds_read_b128 + 4 MFMA ----
    {
      int r0 = wm * 64 + (l & 31);
      int hi = l >> 5;
      bf16x8 a00 = __builtin_bit_cast(bf16x8, A_s[cur][swz(r0,      hi)]);
      bf16x8 a01 = __builtin_bit_cast(bf16x8, A_s[cur][swz(r0,      2 + hi)]);
      bf16x8 a10 = __builtin_bit_cast(bf16x8, A_s[cur][swz(r0 + 32, hi)]);
      bf16x8 a11 = __builtin_bit_cast(bf16x8, A_s[cur][swz(r0 + 32, 2 + hi)]);
      int c0 = wn * 32 + (l & 31);
      bf16x8 b0 = __builtin_bit_cast(bf16x8, B_s[cur][swz(c0, hi)]);
      bf16x8 b1 = __builtin_bit_cast(bf16x8, B_s[cur][swz(c0, 2 + hi)]);
      acc0 = __builtin_amdgcn_mfma_f32_32x32x16_bf16(a00, b0, acc0, 0, 0, 0);
      acc0 = __builtin_amdgcn_mfma_f32_32x32x16_bf16(a01, b1, acc0, 0, 0, 0);
      acc1 = __builtin_amdgcn_mfma_f32_32x32x16_bf16(a10, b0, acc1, 0, 0, 0);
      acc1 = __builtin_amdgcn_mfma_f32_32x32x16_bf16(a11, b1, acc1, 0, 0, 0);
    }
    if (s + 1 < KT) {   // write next buffer
      int nb = cur ^ 1;
      A_s[nb][tid] = av0; A_s[nb][tid + 512] = av1;
      sq += bv.x*bv.x + bv.y*bv.y + bv.z*bv.z + bv.w*bv.w;
      uint2 p; p.x = (unsigned)f2bf(bv.x) | ((unsigned)f2bf(bv.y) << 16);
      p.y = (unsigned)f2bf(bv.z) | ((unsigned)f2bf(bv.w) << 16);
      ((uint2*)B_s[nb])[bslot] = p;
    }
    __syncthreads();
  }

  // ---- concept norms (accumulated for free during staging) ----
  sq += __shfl_xor(sq, 1); sq += __shfl_xor(sq, 2); sq += __shfl_xor(sq, 4);
  if (q == 0) cn_s[brow] = sqrtf(sq);
  __syncthreads();

  // ---- epilogue: cosine + butterfly top-2 across the 32 n-lanes ----
  int half = l >> 5, ln = l & 31;
  int ncol = wn * 32 + ln;
  int n = n0 + ncol;
  float cn = cn_s[ncol];
  bool nvalid = (n < NN);
#pragma unroll
  for (int mf = 0; mf < 2; ++mf) {
#pragma unroll
    for (int r = 0; r < 16; ++r) {
      float dotv = mf ? acc1[r] : acc0[r];
      int m = wm * 64 + mf * 32 + (r & 3) + 8 * (r >> 2) + 4 * half;
      float v1 = nvalid ? dotv / fmaxf(mn_s[m] * cn, 1e-8f) : -INFINITY;
      int i1 = n;
      float v2 = -INFINITY; int i2 = 0x7fffffff;
#pragma unroll
      for (int off = 1; off < 32; off <<= 1) {
        float w1 = __shfl_xor(v1, off); int j1 = __shfl_xor(i1, off);
        float w2 = __shfl_xor(v2, off); int j2 = __shfl_xor(i2, off);
        if (better(w1, j1, v1, i1)) {
          bool t = better(v1, i1, w2, j2);
          float nv2 = t ? v1 : w2; int ni2 = t ? i1 : j2;
          v1 = w1; i1 = j1; v2 = nv2; i2 = ni2;
        } else {
          bool t = better(w1, j1, v2, i2);
          v2 = t ? w1 : v2; i2 = t ? j1 : i2;
        }
      }
      if (ln == 0) red_s[m][wn] = make_float4(v1, __int_as_float(i1), v2, __int_as_float(i2));
    }
  }
  __syncthreads();
  if (tid < BB) {
    float4 e0 = red_s[tid][0], e1 = red_s[tid][1];
    float v1 = e0.x; int i1 = __float_as_int(e0.y);
    float v2 = e0.z; int i2 = __float_as_int(e0.w);
    float w1 = e1.x; int j1 = __float_as_int(e1.y);
    float w2 = e1.z; int j2 = __float_as_int(e1.w);
    float o1, o2; int oi1, oi2;
    if (better(w1, j1, v1, i1)) {
      bool t = better(v1, i1, w2, j2);
      o1 = w1; oi1 = j1; o2 = t ? v1 : w2; oi2 = t ? i1 : j2;
    } else {
      bool t = better(w1, j1, v2, i2);
      o1 = v1; oi1 = i1; o2 = t ? w1 : v2; oi2 = t ? j1 : i2;
    }
    partial[(size_t)tile * BB + tid] = make_float4(o1, __int_as_float(oi1), o2, __int_as_float(oi2));
  }
}

// ---------------- Phase 3: top-8 select + exact fp32 rescore -----------------
__global__ __launch_bounds__(256) void final_kernel(
    const float* __restrict__ dict, const float* __restrict__ repf,
    const float* __restrict__ mnorm, const float4* __restrict__ partial,
    float* __restrict__ out) {
  int m = blockIdx.x, tid = threadIdx.x;
  __shared__ float repL[DD];
  __shared__ float sv[256]; __shared__ int sn[256];
  __shared__ int   seln[8];
  __shared__ float finv[8]; __shared__ int finn[8];
  if (tid < DD) repL[tid] = repf[m * DD + tid];
  __syncthreads();

  for (int r = 0; r < 8; ++r) {
    float bvv = -INFINITY; int bnn = 0x7fffffff;
    for (int t = tid; t < NT; t += 256) {
      float4 e = partial[(size_t)t * BB + m];
      float v1 = e.x; int i1 = __float_as_int(e.y);
      float v2 = e.z; int i2 = __float_as_int(e.w);
      bool ex1 = false, ex2 = false;
      for (int j = 0; j < r; ++j) { ex1 |= (seln[j] == i1); ex2 |= (seln[j] == i2); }
      if (!ex1 && better(v1, i1, bvv, bnn)) { bvv = v1; bnn = i1; }
      if (!ex2 && better(v2, i2, bvv, bnn)) { bvv = v2; bnn = i2; }
    }
    sv[tid] = bvv; sn[tid] = bnn;
    __syncthreads();
    for (int off2 = 128; off2; off2 >>= 1) {
      if (tid < off2) {
        if (better(sv[tid + off2], sn[tid + off2], sv[tid], sn[tid])) {
          sv[tid] = sv[tid + off2]; sn[tid] = sn[tid + off2];
        }
      }
      __syncthreads();
    }
    if (tid == 0) seln[r] = sn[0];
    __syncthreads();
  }

  // 8 half-wave groups rescore the 8 candidates in exact fp32
  int g = tid >> 5, lane = tid & 31;
  int n = seln[g];
  bool ok = (n >= 0 && n < NN);
  float s1 = 0.f, s2 = 0.f;
  if (ok) {
    for (int d = lane; d < DD; d += 32) {
      float b = dict[(size_t)n * DD + d];
      s1 += repL[d] * b; s2 += b * b;
    }
  }
#pragma unroll
  for (int off2 = 16; off2; off2 >>= 1) { s1 += __shfl_xor(s1, off2); s2 += __shfl_xor(s2, off2); }
  if (lane == 0) {
    finv[g] = ok ? s1 / fmaxf(mnorm[m] * sqrtf(s2), 1e-8f) : -INFINITY;
    finn[g] = n;
  }
  __syncthreads();
  if (tid == 0) {
    float bv2 = finv[0]; int bn2 = finn[0];
#pragma unroll
    for (int g2 = 1; g2 < 8; ++g2)
      if (better(finv[g2], finn[g2], bv2, bn2)) { bv2 = finv[g2]; bn2 = finn[g2]; }
    out[m] = bv2;
    out[BB + m] = (float)bn2;   // indices as f32 (flat f32 readback)
  }
}

extern "C" void kernel_launch(void* const* d_in, const int* in_sizes, int n_in,
                              void* d_out, int out_size, void* d_ws, size_t ws_size,
                              hipStream_t stream) {
  const int* ids = (const int*)d_in[0];
  const float* we = (const float*)d_in[1];
  const float* dict = (const float*)d_in[2];
  float* out = (float*)d_out;

  char* ws = (char*)d_ws;
  unsigned short* abf = (unsigned short*)ws;                    // 224*256*2 = 114688
  float* repf  = (float*)(ws + 114688);                         // 204800
  float* mnorm = (float*)(ws + 114688 + 204800);                // 1024
  float4* partial = (float4*)(ws + 114688 + 204800 + 1024);     // 1563*256*16 = 6402048

  prep_kernel<<<BB, 256, 0, stream>>>(ids, we, repf, abf, mnorm);
  sim_kernel<<<NT, 512, 0, stream>>>(dict, (const uint4*)abf, mnorm, partial);
  final_kernel<<<BB, 256, 0, stream>>>(dict, repf, mnorm, partial, out);
}

// Round 3
// 59.132 us; speedup vs baseline: 3.9881x; 3.6793x over previous
//
#include <hip/hip_runtime.h>
#include <math.h>

#define BB 256
#define LL 8
#define DD 200
#define NN 100000
#define KP 224                       // K padded to 7*32
#define NGRAN 28                     // 16B granules (8 bf16) per row
#define BN 64                        // concepts per tile
#define NT ((NN + BN - 1) / BN)      // 1563
#define GRID_SIM 512
#define NCAND 6

typedef __attribute__((ext_vector_type(8))) __bf16 bf16x8;
typedef __attribute__((ext_vector_type(16))) float f32x16;

// fp32 -> bf16 round-to-nearest-even
__device__ __forceinline__ unsigned f2bf(float x) {
  unsigned u = __float_as_uint(x);
  u = (u + 0x7fffu + ((u >> 16) & 1u)) >> 16;
  return u;
}
__device__ __forceinline__ unsigned pk(float a, float b) {
  return f2bf(a) | (f2bf(b) << 16);
}
// numpy argmax semantics: larger wins; exact tie -> smaller index
__device__ __forceinline__ bool better(float a, int ia, float b, int ib) {
  return (a > b) || (a == b && ia < ib);
}
// dict-tile LDS layout: granule-column-major with XOR row swizzle.
// slot(row,g) = g*64 + (row ^ ((2g)&7)): reads (32 rows, fixed g) and writes
// (2 rows x 8 parts) are both <=2-way per 16-lane phase -> free (m136).
__device__ __forceinline__ int bslot(int row, int g) {
  return g * 64 + (row ^ ((2 * g) & 7));
}

// ---------------- Phase 1: mention rep (fp32 + bf16 row-major) ---------------
__global__ __launch_bounds__(256) void prep_kernel(
    const int* __restrict__ ids, const float* __restrict__ we,
    float* __restrict__ repf, unsigned short* __restrict__ abf,
    float* __restrict__ mnorm) {
  int m = blockIdx.x, d = threadIdx.x;
  __shared__ float red[4];
  float r = 0.f;
  if (d < DD) {
    int base = m * LL;
#pragma unroll
    for (int l2 = 0; l2 < LL; ++l2) r += we[(size_t)ids[base + l2] * DD + d];
    r *= 0.125f;
    repf[m * DD + d] = r;
  }
  if (d < KP) abf[m * KP + d] = (unsigned short)f2bf(d < DD ? r : 0.f);
  float sq = (d < DD) ? r * r : 0.f;
#pragma unroll
  for (int off = 32; off; off >>= 1) sq += __shfl_down(sq, off);
  if ((threadIdx.x & 63) == 0) red[threadIdx.x >> 6] = sq;
  __syncthreads();
  if (threadIdx.x == 0) mnorm[m] = sqrtf(red[0] + red[1] + red[2] + red[3]);
}

// ---------------- Phase 2: swapped-operand MFMA sims -------------------------
struct StageRegs { float4 f[8]; float sc; };

__device__ __forceinline__ void stage_load(const float* __restrict__ dict,
                                           int tile, int row, int part,
                                           StageRegs& S) {
  int n = tile * BN + row;
  bool ok = (n < NN);
  S.sc = ok ? 1.f : 0.f;
  const float* src = dict + (size_t)(ok ? n : 0) * DD;
#pragma unroll
  for (int i = 0; i < 3; ++i) {
    int k0 = (part + 8 * i) * 8;
    S.f[2 * i]     = *(const float4*)(src + k0);
    S.f[2 * i + 1] = *(const float4*)(src + k0 + 4);
  }
  if (part == 0) {  // granule 24: k 192..199
    S.f[6] = *(const float4*)(src + 192);
    S.f[7] = *(const float4*)(src + 196);
  }
}

__device__ __forceinline__ void stage_store(const StageRegs& S, uint4* Bsb,
                                            float* rcnb, int row, int part) {
  float sc = S.sc;
  float sq = 0.f;
#pragma unroll
  for (int i = 0; i < 3; ++i) {
    int g = part + 8 * i;
    float4 f0 = S.f[2 * i], f1 = S.f[2 * i + 1];
    float a = f0.x * sc, b = f0.y * sc, c = f0.z * sc, d = f0.w * sc;
    float e = f1.x * sc, h = f1.y * sc, p = f1.z * sc, q = f1.w * sc;
    sq += a * a + b * b + c * c + d * d + e * e + h * h + p * p + q * q;
    uint4 u; u.x = pk(a, b); u.y = pk(c, d); u.z = pk(e, h); u.w = pk(p, q);
    Bsb[bslot(row, g)] = u;
  }
  if (part == 0) {
    float4 f0 = S.f[6], f1 = S.f[7];
    float a = f0.x * sc, b = f0.y * sc, c = f0.z * sc, d = f0.w * sc;
    float e = f1.x * sc, h = f1.y * sc, p = f1.z * sc, q = f1.w * sc;
    sq += a * a + b * b + c * c + d * d + e * e + h * h + p * p + q * q;
    uint4 u; u.x = pk(a, b); u.y = pk(c, d); u.z = pk(e, h); u.w = pk(p, q);
    Bsb[bslot(row, 24)] = u;
  } else if (part < 4) {  // granules 25..27: zero pad
    Bsb[bslot(row, 24 + part)] = make_uint4(0, 0, 0, 0);
  }
  sq += __shfl_xor(sq, 1);
  sq += __shfl_xor(sq, 2);
  sq += __shfl_xor(sq, 4);
  if (part == 0) rcnb[row] = 1.0f / fmaxf(sqrtf(sq), 1e-8f);
}

__global__ __launch_bounds__(512) void sim_kernel(
    const float* __restrict__ dict, const uint4* __restrict__ abf4,
    float4* __restrict__ partial) {
  __shared__ uint4 Bs[2][NGRAN * 64];   // 2 x 28KB
  __shared__ float rcn_s[2][64];

  int tid = threadIdx.x;
  int w = tid >> 6, l = tid & 63;
  int ln = l & 31, kh = l >> 5;
  int m = w * 32 + ln;
  int row = tid >> 3, part = tid & 7;

  // mention fragments in registers: B-operand lane holds col=m, k=kh*8+[0..8)
  uint4 areg[14];
#pragma unroll
  for (int s = 0; s < 7; ++s)
#pragma unroll
    for (int h = 0; h < 2; ++h)
      areg[s * 2 + h] = abf4[m * NGRAN + s * 4 + h * 2 + kh];

  float v1 = -INFINITY, v2 = -INFINITY;
  int i1 = 0x7fffffff, i2 = 0x7fffffff;

  int t0 = blockIdx.x;
  StageRegs S;
  stage_load(dict, t0, row, part, S);
  stage_store(S, Bs[0], rcn_s[0], row, part);
  __syncthreads();

  int cur = 0;
  for (int t = t0; t < NT; t += GRID_SIM) {
    bool nxt = (t + GRID_SIM) < NT;
    if (nxt) stage_load(dict, t + GRID_SIM, row, part, S);

    f32x16 acc0, acc1;
#pragma unroll
    for (int i = 0; i < 16; ++i) { acc0[i] = 0.f; acc1[i] = 0.f; }
    const uint4* B = Bs[cur];
#pragma unroll
    for (int s = 0; s < 7; ++s) {
#pragma unroll
      for (int h = 0; h < 2; ++h) {
        int g = s * 4 + h * 2 + kh;
        int xr = ln ^ ((2 * g) & 7);
        bf16x8 d0 = __builtin_bit_cast(bf16x8, B[g * 64 + xr]);
        bf16x8 d1 = __builtin_bit_cast(bf16x8, B[g * 64 + 32 + xr]);
        bf16x8 mb = __builtin_bit_cast(bf16x8, areg[s * 2 + h]);
        acc0 = __builtin_amdgcn_mfma_f32_32x32x16_bf16(d0, mb, acc0, 0, 0, 0);
        acc1 = __builtin_amdgcn_mfma_f32_32x32x16_bf16(d1, mb, acc1, 0, 0, 0);
      }
    }

    // lane-local top-2 (n monotone increasing per lane -> ties keep smaller n)
    int n0 = t * BN;
    const float* rc = rcn_s[cur];
#pragma unroll
    for (int r = 0; r < 16; ++r) {
      int nl = (r & 3) + 8 * (r >> 2) + 4 * kh;
      int n = n0 + nl;
      float v = acc0[r] * rc[nl];
      v = (n < NN) ? v : -INFINITY;
      if (v > v1) { v2 = v1; i2 = i1; v1 = v; i1 = n; }
      else if (v > v2) { v2 = v; i2 = n; }
    }
#pragma unroll
    for (int r = 0; r < 16; ++r) {
      int nl = 32 + (r & 3) + 8 * (r >> 2) + 4 * kh;
      int n = n0 + nl;
      float v = acc1[r] * rc[nl];
      v = (n < NN) ? v : -INFINITY;
      if (v > v1) { v2 = v1; i2 = i1; v1 = v; i1 = n; }
      else if (v > v2) { v2 = v; i2 = n; }
    }

    if (nxt) stage_store(S, Bs[cur ^ 1], rcn_s[cur ^ 1], row, part);
    __syncthreads();
    cur ^= 1;
  }

  // merge the two kh-halves (same m, disjoint n sets): one shuffle step
  float w1 = __shfl_xor(v1, 32); int j1 = __shfl_xor(i1, 32);
  float w2 = __shfl_xor(v2, 32); int j2 = __shfl_xor(i2, 32);
  float o1, o2; int oi1, oi2;
  if (better(w1, j1, v1, i1)) {
    bool tt = better(v1, i1, w2, j2);
    o1 = w1; oi1 = j1; o2 = tt ? v1 : w2; oi2 = tt ? i1 : j2;
  } else {
    bool tt = better(w1, j1, v2, i2);
    o1 = v1; oi1 = i1; o2 = tt ? w1 : v2; oi2 = tt ? j1 : i2;
  }
  if (kh == 0)
    partial[(size_t)m * GRID_SIM + blockIdx.x] =
        make_float4(o1, __int_as_float(oi1), o2, __int_as_float(oi2));
}

// ---------------- Phase 3: top-6 select + exact fp32 rescore -----------------
__global__ __launch_bounds__(256) void final_kernel(
    const float* __restrict__ dict, const float* __restrict__ repf,
    const float* __restrict__ mnorm, const float4* __restrict__ partial,
    float* __restrict__ out) {
  int m = blockIdx.x, tid = threadIdx.x;
  __shared__ float repL[DD];
  __shared__ int seln[NCAND];
  __shared__ float wv[4]; __shared__ int wi[4];
  __shared__ float finv[NCAND]; __shared__ int finn[NCAND];
  if (tid < DD) repL[tid] = repf[m * DD + tid];
  if (tid < NCAND) seln[tid] = -1;
  __syncthreads();

  const float4* pm = partial + (size_t)m * GRID_SIM;
  for (int r = 0; r < NCAND; ++r) {
    float bv = -INFINITY; int bi = 0x7fffffff;
#pragma unroll
    for (int e = 0; e < 2; ++e) {
      float4 E = pm[tid + e * 256];
      float a1 = E.x; int c1 = __float_as_int(E.y);
      float a2 = E.z; int c2 = __float_as_int(E.w);
      bool ex1 = false, ex2 = false;
#pragma unroll
      for (int j = 0; j < NCAND; ++j) {
        int s = seln[j];
        ex1 |= (s == c1); ex2 |= (s == c2);
      }
      if (!ex1 && better(a1, c1, bv, bi)) { bv = a1; bi = c1; }
      if (!ex2 && better(a2, c2, bv, bi)) { bv = a2; bi = c2; }
    }
#pragma unroll
    for (int off = 1; off < 64; off <<= 1) {
      float ov = __shfl_xor(bv, off); int oi = __shfl_xor(bi, off);
      if (better(ov, oi, bv, bi)) { bv = ov; bi = oi; }
    }
    if ((tid & 63) == 0) { wv[tid >> 6] = bv; wi[tid >> 6] = bi; }
    __syncthreads();
    if (tid == 0) {
      float Bv = wv[0]; int Bi = wi[0];
#pragma unroll
      for (int q = 1; q < 4; ++q)
        if (better(wv[q], wi[q], Bv, Bi)) { Bv = wv[q]; Bi = wi[q]; }
      seln[r] = Bi;
    }
    __syncthreads();
  }

  // exact fp32 rescore of the NCAND candidates: one 32-lane group each
  int g = tid >> 5, lane = tid & 31;
  int n = (g < NCAND) ? seln[g] : -1;
  float s1 = 0.f, s2 = 0.f;
  if (n >= 0) {
    for (int d = lane; d < DD; d += 32) {
      float b = dict[(size_t)n * DD + d];
      s1 += repL[d] * b; s2 += b * b;
    }
  }
#pragma unroll
  for (int off = 1; off < 32; off <<= 1) {
    s1 += __shfl_xor(s1, off); s2 += __shfl_xor(s2, off);
  }
  if (lane == 0 && g < NCAND) {
    finv[g] = (n >= 0) ? s1 / fmaxf(mnorm[m] * sqrtf(s2), 1e-8f) : -INFINITY;
    finn[g] = n;
  }
  __syncthreads();
  if (tid == 0) {
    float Bv = finv[0]; int Bi = finn[0];
#pragma unroll
    for (int q = 1; q < NCAND; ++q)
      if (better(finv[q], finn[q], Bv, Bi)) { Bv = finv[q]; Bi = finn[q]; }
    out[m] = Bv;
    out[BB + m] = (float)Bi;  // indices as f32 (flat f32 readback)
  }
}

extern "C" void kernel_launch(void* const* d_in, const int* in_sizes, int n_in,
                              void* d_out, int out_size, void* d_ws, size_t ws_size,
                              hipStream_t stream) {
  const int* ids = (const int*)d_in[0];
  const float* we = (const float*)d_in[1];
  const float* dict = (const float*)d_in[2];
  float* out = (float*)d_out;

  char* ws = (char*)d_ws;
  unsigned short* abf = (unsigned short*)ws;              // 256*224*2 = 114688
  float* repf  = (float*)(ws + 114688);                   // 204800
  float* mnorm = (float*)(ws + 319488);                   // 1024
  float4* partial = (float4*)(ws + 320512);               // 256*512*16 = 2097152

  prep_kernel<<<BB, 256, 0, stream>>>(ids, we, repf, abf, mnorm);
  sim_kernel<<<GRID_SIM, 512, 0, stream>>>(dict, (const uint4*)abf, partial);
  final_kernel<<<BB, 256, 0, stream>>>(dict, repf, mnorm, partial, out);
}